// Round 12
// baseline (204.547 us; speedup 1.0000x reference)
//
#include <hip/hip_runtime.h>
#include <math.h>

constexpr int IN_F  = 128;
constexpr int OUT_F = 64;
constexpr int HEADS = 4;
constexpr int COLS  = HEADS * OUT_F;   // 256
constexpr float ALPHA = 0.2f;
constexpr int HIST_BLOCKS = 1024;

typedef __attribute__((ext_vector_type(8))) short short8v;   // 8 bf16 = 4 VGPR
typedef __attribute__((ext_vector_type(4))) float f32x4;

__device__ inline unsigned short f2bf(float f) {   // round-to-nearest-even
  unsigned int u = __float_as_uint(f);
  u += 0x7FFF + ((u >> 16) & 1);
  return (unsigned short)(u >> 16);
}
__device__ inline float bf2f(unsigned short s) {
  return __uint_as_float((unsigned int)s << 16);
}

__device__ inline int wave_incl_scan(int v, int lane) {
  #pragma unroll
  for (int ofs = 1; ofs < 64; ofs <<= 1) {
    int tv = __shfl_up(v, ofs, 64);
    if (lane >= ofs) v += tv;
  }
  return v;
}

__device__ inline void fma8(float* acc, float p, const uint4 xv) {
  acc[0] += p * __uint_as_float(xv.x << 16);
  acc[1] += p * __uint_as_float(xv.x & 0xFFFF0000u);
  acc[2] += p * __uint_as_float(xv.y << 16);
  acc[3] += p * __uint_as_float(xv.y & 0xFFFF0000u);
  acc[4] += p * __uint_as_float(xv.z << 16);
  acc[5] += p * __uint_as_float(xv.z & 0xFFFF0000u);
  acc[6] += p * __uint_as_float(xv.w << 16);
  acc[7] += p * __uint_as_float(xv.w & 0xFFFF0000u);
}

// ---------------------------------------------------------------------------
// k_prep: zero deg + done-counter, convert W[h][i][o] f32 -> Wb[h][o][i] bf16
// ---------------------------------------------------------------------------
__global__ __launch_bounds__(256) void k_prep(const float* __restrict__ W,
                                              unsigned short* __restrict__ Wb,
                                              int* __restrict__ deg,
                                              int* __restrict__ done, int n) {
  int i = blockIdx.x * 256 + threadIdx.x;
  if (i < n) deg[i] = 0;
  if (i == 0) *done = 0;
  if (i < HEADS * IN_F * OUT_F) {
    int h = i >> 13;
    int o = (i >> 7) & 63;
    int k = i & 127;
    Wb[i] = f2bf(W[(size_t)h * 8192 + k * 64 + o]);
  }
}

// ---------------------------------------------------------------------------
// k_big: blocks [0, GB): MFMA GEMM (64 rows x 256 cols, wave = head);
//        blocks [GB, GB+HIST_BLOCKS): degree histogram (grid-stride).
// 32KB LDS via aliasing x-staging (dead after MFMA loop) with out staging.
// Scores stored as bf16 TRANSPOSED per-head planes sT[h][node] (100KB/head)
// so k_aggr's per-XCD score footprint is tiny.
// ---------------------------------------------------------------------------
__global__ __launch_bounds__(256) void k_big(const float* __restrict__ x,
                                             const unsigned short* __restrict__ Wb,
                                             const float* __restrict__ a,
                                             const int* __restrict__ ei,
                                             unsigned short* __restrict__ xtb,
                                             unsigned short* __restrict__ s_srcT,
                                             unsigned short* __restrict__ s_dstT,
                                             int* __restrict__ deg,
                                             int n, int E, int GB) {
  __shared__ unsigned short sm[64 * 256];     // 32KB: xls (first 16KB), then ols
  const int bid = blockIdx.x;
  const int t = threadIdx.x;

  if (bid >= GB) {
    int db = bid - GB;
    for (int e = db * 256 + t; e < E; e += HIST_BLOCKS * 256)
      atomicAdd(&deg[ei[E + e]], 1);
    return;
  }

  const int rbase = bid * 64;
  const int lane = t & 63;
  const int w = t >> 6;                       // wave id = head

  // stage x tile -> bf16 swizzled LDS (first 16KB of sm)
  for (int c = t; c < 2048; c += 256) {
    int row = c >> 5;
    int i4  = c & 31;
    int grow = rbase + row;
    float4 v = make_float4(0.f, 0.f, 0.f, 0.f);
    if (grow < n) v = *(const float4*)(x + (size_t)grow * IN_F + i4 * 4);
    unsigned int p0 = (unsigned int)f2bf(v.x) | ((unsigned int)f2bf(v.y) << 16);
    unsigned int p1 = (unsigned int)f2bf(v.z) | ((unsigned int)f2bf(v.w) << 16);
    int byte = row * 256 + ((i4 * 8) ^ ((row & 7) << 4));
    *(uint2*)((char*)sm + byte) = make_uint2(p0, p1);
  }
  __syncthreads();

  const unsigned short* Wh = Wb + (size_t)w * 8192;
  const int nfix = lane & 15;
  const int kg   = lane >> 4;

  f32x4 acc[4][4] = {};   // [mi][ni]

  #pragma unroll
  for (int kk = 0; kk < 4; ++kk) {
    short8v bfrag[4];
    #pragma unroll
    for (int ni = 0; ni < 4; ++ni)
      bfrag[ni] = *(const short8v*)(Wh + (ni * 16 + nfix) * 128 + kk * 32 + kg * 8);
    #pragma unroll
    for (int mi = 0; mi < 4; ++mi) {
      int m = mi * 16 + nfix;
      int abyte = m * 256 + ((kk * 64 + kg * 16) ^ ((m & 7) << 4));
      short8v afrag = *(const short8v*)((char*)sm + abyte);
      #pragma unroll
      for (int ni = 0; ni < 4; ++ni)
        acc[mi][ni] = __builtin_amdgcn_mfma_f32_16x16x32_bf16(
            afrag, bfrag[ni], acc[mi][ni], 0, 0, 0);
    }
  }

  // epilogue B: score projections -> bf16 transposed planes
  float as[4], ad[4];
  #pragma unroll
  for (int ni = 0; ni < 4; ++ni) {
    as[ni] = a[w * 128 + ni * 16 + nfix];
    ad[ni] = a[w * 128 + 64 + ni * 16 + nfix];
  }
  #pragma unroll
  for (int mi = 0; mi < 4; ++mi) {
    #pragma unroll
    for (int r = 0; r < 4; ++r) {
      float ps = 0.f, pd = 0.f;
      #pragma unroll
      for (int ni = 0; ni < 4; ++ni) {
        ps += acc[mi][ni][r] * as[ni];
        pd += acc[mi][ni][r] * ad[ni];
      }
      #pragma unroll
      for (int m = 1; m < 16; m <<= 1) {
        ps += __shfl_xor(ps, m);
        pd += __shfl_xor(pd, m);
      }
      if ((lane & 15) == 0) {
        int row = rbase + mi * 16 + (kg << 2) + r;
        if (row < n) {
          s_srcT[(size_t)w * n + row] = f2bf(ps);
          s_dstT[(size_t)w * n + row] = f2bf(pd);
        }
      }
    }
  }

  __syncthreads();   // xls region dead; reuse sm as output staging

  // epilogue A: dump acc (bf16) to swizzled LDS, then coalesced 16B stores
  #pragma unroll
  for (int mi = 0; mi < 4; ++mi)
    #pragma unroll
    for (int ni = 0; ni < 4; ++ni)
      #pragma unroll
      for (int r = 0; r < 4; ++r) {
        int row = mi * 16 + (kg << 2) + r;
        int col = (w << 6) + ni * 16 + nfix;
        int byte = row * 512 + ((col * 2) ^ (((row >> 2) & 3) << 5));
        *(unsigned short*)((char*)sm + byte) = f2bf(acc[mi][ni][r]);
      }
  __syncthreads();
  for (int c = t; c < 2048; c += 256) {
    int row = c >> 5;
    int ch  = c & 31;
    int grow = rbase + row;
    if (grow < n) {
      int byte = row * 512 + ((ch * 16) ^ (((row >> 2) & 3) << 5));
      *(uint4*)(xtb + (size_t)grow * COLS + ch * 8) =
          *(const uint4*)((const char*)sm + byte);
    }
  }
}

// ---------------------------------------------------------------------------
// k_scanA: per-256-chunk sums -> part[]; LAST block scans part[] (exclusive).
// ---------------------------------------------------------------------------
__global__ __launch_bounds__(256) void k_scanA(const int* __restrict__ deg,
                                               int* __restrict__ part,
                                               int* __restrict__ done,
                                               int n, int nparts) {
  __shared__ int wt[4];
  __shared__ int isLast;
  const int tid = threadIdx.x;
  const int lane = tid & 63;
  const int wid = tid >> 6;

  int i = blockIdx.x * 256 + tid;
  int v = (i < n) ? deg[i] : 0;
  int s = v;
  #pragma unroll
  for (int m = 1; m < 64; m <<= 1) s += __shfl_xor(s, m);
  if (lane == 0) wt[wid] = s;
  __syncthreads();
  if (tid == 0) {
    atomicExch(&part[blockIdx.x], wt[0] + wt[1] + wt[2] + wt[3]);
    __threadfence();
    isLast = (atomicAdd(done, 1) == nparts - 1);
  }
  __syncthreads();
  if (!isLast) return;

  int pv = (tid < nparts) ? atomicAdd(&part[tid], 0) : 0;
  int incl = wave_incl_scan(pv, lane);
  __syncthreads();
  if (lane == 63) wt[wid] = incl;
  __syncthreads();
  int wofs = 0;
  #pragma unroll
  for (int w = 0; w < 4; ++w) wofs += (w < wid) ? wt[w] : 0;
  if (tid < nparts) atomicExch(&part[tid], wofs + incl - pv);
}

// ---------------------------------------------------------------------------
// k_scanB: per-chunk exclusive scan + block offset -> cursor (= CSR start)
// ---------------------------------------------------------------------------
__global__ __launch_bounds__(256) void k_scanB(const int* __restrict__ deg,
                                               const int* __restrict__ part,
                                               int* __restrict__ cursor, int n) {
  __shared__ int wt[4];
  int i = blockIdx.x * 256 + threadIdx.x;
  int lane = threadIdx.x & 63;
  int wid = threadIdx.x >> 6;
  int v = (i < n) ? deg[i] : 0;
  int incl = wave_incl_scan(v, lane);
  if (lane == 63) wt[wid] = incl;
  __syncthreads();
  int wofs = 0;
  #pragma unroll
  for (int w = 0; w < 4; ++w) wofs += (w < wid) ? wt[w] : 0;
  if (i < n) cursor[i] = part[blockIdx.x] + wofs + incl - v;
}

// ---------------------------------------------------------------------------
// k_scatter: one edge per thread; csr16 entries hold src node id (ushort)
// ---------------------------------------------------------------------------
__global__ __launch_bounds__(256) void k_scatter(const int* __restrict__ ei,
                                                 int* __restrict__ cursor,
                                                 unsigned short* __restrict__ csr16,
                                                 int E) {
  int e = blockIdx.x * 256 + threadIdx.x;
  if (e >= E) return;
  int src = ei[e];
  int dst = ei[E + e];
  int pos = atomicAdd(&cursor[dst], 1);
  csr16[pos] = (unsigned short)src;
}

// ---------------------------------------------------------------------------
// k_aggr v6 (XCD-sliced): bid&7 = column slice (32 cols = 64B of xtb row).
// blockIdx round-robins across XCDs -> each XCD touches only its slice:
// 50000*64B = 3.2MB -> L2-resident; gathers served at L2 BW, not L3.
// Wave = 16 nodes (4-lane group per node, consecutive -> csr streamed).
// No cross-group reduce: psum is group-local.
// ---------------------------------------------------------------------------
__global__ __launch_bounds__(256) void k_aggr(const unsigned short* __restrict__ csr16,
                                              const int* __restrict__ cursor,
                                              const int* __restrict__ deg,
                                              const unsigned short* __restrict__ s_srcT,
                                              const unsigned short* __restrict__ s_dstT,
                                              const unsigned short* __restrict__ xtb,
                                              float* __restrict__ out, int n) {
  const int slice = blockIdx.x & 7;           // XCD-pinned column slice
  const int lane  = threadIdx.x & 63;
  const int wid   = threadIdx.x >> 6;
  const int grp   = lane >> 2;                // node subgroup 0..15
  const int sub   = lane & 3;                 // 16B chunk within 64B slice
  const int node  = (blockIdx.x >> 3) * 64 + wid * 16 + grp;
  const int h     = slice >> 1;               // head of this slice
  if (node >= n) return;

  const unsigned short* sS = s_srcT + (size_t)h * n;

  int eEnd = cursor[node];
  int d    = deg[node];
  int j    = eEnd - d;
  float sd = bf2f(s_dstT[(size_t)h * n + node]);

  float acc[8] = {};
  float psum = 0.f;
  const char* xb = (const char*)xtb + slice * 64 + sub * 16;

  #pragma unroll 2
  for (; j < eEnd; ++j) {
    int src = csr16[j];
    float sc = bf2f(sS[src]);
    float v = sc + sd; v = v >= 0.f ? v : ALPHA * v;
    float p = __expf(v);
    psum += p;
    uint4 r = *(const uint4*)(xb + src * 512);
    fma8(acc, p, r);
  }

  float inv = 1.f / (psum + 1e-10f);
  float* op = out + (size_t)node * COLS + slice * 32 + sub * 8;
  *(float4*)op       = make_float4(acc[0] * inv, acc[1] * inv, acc[2] * inv, acc[3] * inv);
  *(float4*)(op + 4) = make_float4(acc[4] * inv, acc[5] * inv, acc[6] * inv, acc[7] * inv);
}

// ---------------------------------------------------------------------------
extern "C" void kernel_launch(void* const* d_in, const int* in_sizes, int n_in,
                              void* d_out, int out_size, void* d_ws, size_t ws_size,
                              hipStream_t stream) {
  const float* x  = (const float*)d_in[0];
  const int*   ei = (const int*)d_in[1];
  const float* W  = (const float*)d_in[2];
  const float* a  = (const float*)d_in[3];
  float* out = (float*)d_out;

  const int n = in_sizes[0] / IN_F;   // 50000
  const int E = in_sizes[1] / 2;      // 800000
  const int nparts = (n + 255) / 256; // 196 scan chunks
  const int GB = (n + 63) / 64;       // 782 gemm blocks

  char* ws = (char*)d_ws;
  size_t off = 0;
  unsigned short* xtb = (unsigned short*)(ws + off); off += (size_t)n * COLS * 2;  // 25.6 MB
  unsigned short* Wb  = (unsigned short*)(ws + off); off += (size_t)HEADS * IN_F * OUT_F * 2;
  unsigned short* s_srcT = (unsigned short*)(ws + off); off += (size_t)n * HEADS * 2;
  unsigned short* s_dstT = (unsigned short*)(ws + off); off += (size_t)n * HEADS * 2;
  int* deg = (int*)(ws + off);         off += (size_t)n * 4;
  int* done = (int*)(ws + off);        off += 256;               // scan done-counter
  int* cursor = (int*)(ws + off);      off += (size_t)n * 4;
  int* part = (int*)(ws + off);        off += (size_t)nparts * 4;
  unsigned short* csr16 = (unsigned short*)(ws + off); off += (size_t)E * 2;

  k_prep<<<nparts, 256, 0, stream>>>(W, Wb, deg, done, n);

  k_big<<<GB + HIST_BLOCKS, 256, 0, stream>>>(x, Wb, a, ei, xtb, s_srcT, s_dstT,
                                              deg, n, E, GB);

  k_scanA<<<nparts, 256, 0, stream>>>(deg, part, done, n, nparts);
  k_scanB<<<nparts, 256, 0, stream>>>(deg, part, cursor, n);

  k_scatter<<<(E + 255) / 256, 256, 0, stream>>>(ei, cursor, csr16, E);

  k_aggr<<<GB * 8, 256, 0, stream>>>(csr16, cursor, deg, s_srcT, s_dstT, xtb, out, n);
}

// Round 13
// 146.642 us; speedup vs baseline: 1.3949x; 1.3949x over previous
//
#include <hip/hip_runtime.h>
#include <math.h>

constexpr int IN_F  = 128;
constexpr int OUT_F = 64;
constexpr int HEADS = 4;
constexpr int COLS  = HEADS * OUT_F;   // 256
constexpr float ALPHA = 0.2f;
constexpr int HIST_BLOCKS = 1024;

typedef __attribute__((ext_vector_type(8))) short short8v;   // 8 bf16 = 4 VGPR
typedef __attribute__((ext_vector_type(4))) float f32x4;

__device__ inline unsigned short f2bf(float f) {   // round-to-nearest-even
  unsigned int u = __float_as_uint(f);
  u += 0x7FFF + ((u >> 16) & 1);
  return (unsigned short)(u >> 16);
}

__device__ inline int wave_incl_scan(int v, int lane) {
  #pragma unroll
  for (int ofs = 1; ofs < 64; ofs <<= 1) {
    int tv = __shfl_up(v, ofs, 64);
    if (lane >= ofs) v += tv;
  }
  return v;
}

__device__ inline void fma8(float* acc, float p, const uint4 xv) {
  acc[0] += p * __uint_as_float(xv.x << 16);
  acc[1] += p * __uint_as_float(xv.x & 0xFFFF0000u);
  acc[2] += p * __uint_as_float(xv.y << 16);
  acc[3] += p * __uint_as_float(xv.y & 0xFFFF0000u);
  acc[4] += p * __uint_as_float(xv.z << 16);
  acc[5] += p * __uint_as_float(xv.z & 0xFFFF0000u);
  acc[6] += p * __uint_as_float(xv.w << 16);
  acc[7] += p * __uint_as_float(xv.w & 0xFFFF0000u);
}

// ---------------------------------------------------------------------------
// k_prep: zero deg + done-counter, convert W[h][i][o] f32 -> Wb[h][o][i] bf16
// ---------------------------------------------------------------------------
__global__ __launch_bounds__(256) void k_prep(const float* __restrict__ W,
                                              unsigned short* __restrict__ Wb,
                                              int* __restrict__ deg,
                                              int* __restrict__ done, int n) {
  int i = blockIdx.x * 256 + threadIdx.x;
  if (i < n) deg[i] = 0;
  if (i == 0) *done = 0;
  if (i < HEADS * IN_F * OUT_F) {
    int h = i >> 13;
    int o = (i >> 7) & 63;
    int k = i & 127;
    Wb[i] = f2bf(W[(size_t)h * 8192 + k * 64 + o]);
  }
}

// ---------------------------------------------------------------------------
// k_big: blocks [0, GB): MFMA GEMM (64 rows x 256 cols, wave = head);
//        blocks [GB, GB+HIST_BLOCKS): degree histogram (grid-stride), which
//        ALSO records each edge's rank within its dst (atomic return value)
//        -> k_scatter needs no atomics.
// ---------------------------------------------------------------------------
__global__ __launch_bounds__(256) void k_big(const float* __restrict__ x,
                                             const unsigned short* __restrict__ Wb,
                                             const float* __restrict__ a,
                                             const int* __restrict__ ei,
                                             unsigned short* __restrict__ xtb,
                                             float* __restrict__ s_src,
                                             float* __restrict__ s_dst,
                                             int* __restrict__ deg,
                                             unsigned short* __restrict__ rank16,
                                             int n, int E, int GB) {
  __shared__ unsigned short sm[64 * 256];     // 32KB: xls (first 16KB), then ols
  const int bid = blockIdx.x;
  const int t = threadIdx.x;

  if (bid >= GB) {
    int db = bid - GB;
    for (int e = db * 256 + t; e < E; e += HIST_BLOCKS * 256) {
      int r = atomicAdd(&deg[ei[E + e]], 1);
      rank16[e] = (unsigned short)r;          // coalesced 2B write
    }
    return;
  }

  const int rbase = bid * 64;
  const int lane = t & 63;
  const int w = t >> 6;                       // wave id = head

  // stage x tile -> bf16 swizzled LDS (first 16KB of sm)
  for (int c = t; c < 2048; c += 256) {
    int row = c >> 5;
    int i4  = c & 31;
    int grow = rbase + row;
    float4 v = make_float4(0.f, 0.f, 0.f, 0.f);
    if (grow < n) v = *(const float4*)(x + (size_t)grow * IN_F + i4 * 4);
    unsigned int p0 = (unsigned int)f2bf(v.x) | ((unsigned int)f2bf(v.y) << 16);
    unsigned int p1 = (unsigned int)f2bf(v.z) | ((unsigned int)f2bf(v.w) << 16);
    int byte = row * 256 + ((i4 * 8) ^ ((row & 7) << 4));
    *(uint2*)((char*)sm + byte) = make_uint2(p0, p1);
  }
  __syncthreads();

  const unsigned short* Wh = Wb + (size_t)w * 8192;
  const int nfix = lane & 15;
  const int kg   = lane >> 4;

  f32x4 acc[4][4] = {};   // [mi][ni]

  #pragma unroll
  for (int kk = 0; kk < 4; ++kk) {
    short8v bfrag[4];
    #pragma unroll
    for (int ni = 0; ni < 4; ++ni)
      bfrag[ni] = *(const short8v*)(Wh + (ni * 16 + nfix) * 128 + kk * 32 + kg * 8);
    #pragma unroll
    for (int mi = 0; mi < 4; ++mi) {
      int m = mi * 16 + nfix;
      int abyte = m * 256 + ((kk * 64 + kg * 16) ^ ((m & 7) << 4));
      short8v afrag = *(const short8v*)((char*)sm + abyte);
      #pragma unroll
      for (int ni = 0; ni < 4; ++ni)
        acc[mi][ni] = __builtin_amdgcn_mfma_f32_16x16x32_bf16(
            afrag, bfrag[ni], acc[mi][ni], 0, 0, 0);
    }
  }

  // epilogue B: score projections from f32 accumulators (no LDS)
  float as[4], ad[4];
  #pragma unroll
  for (int ni = 0; ni < 4; ++ni) {
    as[ni] = a[w * 128 + ni * 16 + nfix];
    ad[ni] = a[w * 128 + 64 + ni * 16 + nfix];
  }
  #pragma unroll
  for (int mi = 0; mi < 4; ++mi) {
    #pragma unroll
    for (int r = 0; r < 4; ++r) {
      float ps = 0.f, pd = 0.f;
      #pragma unroll
      for (int ni = 0; ni < 4; ++ni) {
        ps += acc[mi][ni][r] * as[ni];
        pd += acc[mi][ni][r] * ad[ni];
      }
      #pragma unroll
      for (int m = 1; m < 16; m <<= 1) {
        ps += __shfl_xor(ps, m);
        pd += __shfl_xor(pd, m);
      }
      if ((lane & 15) == 0) {
        int row = rbase + mi * 16 + (kg << 2) + r;
        if (row < n) {
          s_src[(size_t)row * 4 + w] = ps;
          s_dst[(size_t)row * 4 + w] = pd;
        }
      }
    }
  }

  __syncthreads();   // xls region dead; reuse sm as output staging

  // epilogue A: dump acc (bf16) to swizzled LDS, then coalesced 16B stores
  #pragma unroll
  for (int mi = 0; mi < 4; ++mi)
    #pragma unroll
    for (int ni = 0; ni < 4; ++ni)
      #pragma unroll
      for (int r = 0; r < 4; ++r) {
        int row = mi * 16 + (kg << 2) + r;
        int col = (w << 6) + ni * 16 + nfix;
        int byte = row * 512 + ((col * 2) ^ (((row >> 2) & 3) << 5));
        *(unsigned short*)((char*)sm + byte) = f2bf(acc[mi][ni][r]);
      }
  __syncthreads();
  for (int c = t; c < 2048; c += 256) {
    int row = c >> 5;
    int ch  = c & 31;
    int grow = rbase + row;
    if (grow < n) {
      int byte = row * 512 + ((ch * 16) ^ (((row >> 2) & 3) << 5));
      *(uint4*)(xtb + (size_t)grow * COLS + ch * 8) =
          *(const uint4*)((const char*)sm + byte);
    }
  }
}

// ---------------------------------------------------------------------------
// k_scanA: per-256-chunk sums -> part[]; LAST block scans part[] (exclusive).
// ---------------------------------------------------------------------------
__global__ __launch_bounds__(256) void k_scanA(const int* __restrict__ deg,
                                               int* __restrict__ part,
                                               int* __restrict__ done,
                                               int n, int nparts) {
  __shared__ int wt[4];
  __shared__ int isLast;
  const int tid = threadIdx.x;
  const int lane = tid & 63;
  const int wid = tid >> 6;

  int i = blockIdx.x * 256 + tid;
  int v = (i < n) ? deg[i] : 0;
  int s = v;
  #pragma unroll
  for (int m = 1; m < 64; m <<= 1) s += __shfl_xor(s, m);
  if (lane == 0) wt[wid] = s;
  __syncthreads();
  if (tid == 0) {
    atomicExch(&part[blockIdx.x], wt[0] + wt[1] + wt[2] + wt[3]);
    __threadfence();
    isLast = (atomicAdd(done, 1) == nparts - 1);
  }
  __syncthreads();
  if (!isLast) return;

  int pv = (tid < nparts) ? atomicAdd(&part[tid], 0) : 0;
  int incl = wave_incl_scan(pv, lane);
  __syncthreads();
  if (lane == 63) wt[wid] = incl;
  __syncthreads();
  int wofs = 0;
  #pragma unroll
  for (int w = 0; w < 4; ++w) wofs += (w < wid) ? wt[w] : 0;
  if (tid < nparts) atomicExch(&part[tid], wofs + incl - pv);
}

// ---------------------------------------------------------------------------
// k_scanB: per-chunk exclusive scan + block offset -> start (= CSR start)
// ---------------------------------------------------------------------------
__global__ __launch_bounds__(256) void k_scanB(const int* __restrict__ deg,
                                               const int* __restrict__ part,
                                               int* __restrict__ start, int n) {
  __shared__ int wt[4];
  int i = blockIdx.x * 256 + threadIdx.x;
  int lane = threadIdx.x & 63;
  int wid = threadIdx.x >> 6;
  int v = (i < n) ? deg[i] : 0;
  int incl = wave_incl_scan(v, lane);
  if (lane == 63) wt[wid] = incl;
  __syncthreads();
  int wofs = 0;
  #pragma unroll
  for (int w = 0; w < 4; ++w) wofs += (w < wid) ? wt[w] : 0;
  if (i < n) start[i] = part[blockIdx.x] + wofs + incl - v;
}

// ---------------------------------------------------------------------------
// k_scatter (atomic-free): pos = start[dst] + rank16[e]; csr16[pos] = src.
// ---------------------------------------------------------------------------
__global__ __launch_bounds__(256) void k_scatter(const int* __restrict__ ei,
                                                 const int* __restrict__ start,
                                                 const unsigned short* __restrict__ rank16,
                                                 unsigned short* __restrict__ csr16,
                                                 int E) {
  int e = blockIdx.x * 256 + threadIdx.x;
  if (e >= E) return;
  int src = ei[e];
  int dst = ei[E + e];
  int pos = start[dst] + (int)rank16[e];
  csr16[pos] = (unsigned short)src;
}

// ---------------------------------------------------------------------------
// k_aggr v5: one wave per dst node (128-thread blocks, 2 waves); halves own
// alternating edges; each half keeps FOUR edges in flight (8 chains/wave).
// ---------------------------------------------------------------------------
__global__ __launch_bounds__(128) void k_aggr(const unsigned short* __restrict__ csr16,
                                              const int* __restrict__ start,
                                              const int* __restrict__ deg,
                                              const float* __restrict__ s_src,
                                              const float* __restrict__ s_dst,
                                              const unsigned short* __restrict__ xtb,
                                              float* __restrict__ out, int n) {
  int node = (blockIdx.x * 128 + threadIdx.x) >> 6;
  if (node >= n) return;
  int lane = threadIdx.x & 63;
  int half = lane >> 5;       // 0 or 1
  int g    = lane & 31;
  int h    = g >> 3;          // head of this 8-lane column group
  int cb2  = g << 4;          // byte offset of col base

  int s    = start[node];
  int eEnd = s + deg[node];
  float sd = s_dst[node * 4 + h];

  float acc[8] = {};
  float psum = 0.f;
  const char* xb = (const char*)xtb;

  int j = s + half;
  while (j + 6 < eEnd) {
    int o0 = ((int)csr16[j])     << 9;
    int o1 = ((int)csr16[j + 2]) << 9;
    int o2 = ((int)csr16[j + 4]) << 9;
    int o3 = ((int)csr16[j + 6]) << 9;
    float sc0 = s_src[(o0 >> 7) + h];
    float sc1 = s_src[(o1 >> 7) + h];
    float sc2 = s_src[(o2 >> 7) + h];
    float sc3 = s_src[(o3 >> 7) + h];
    uint4 r0 = *(const uint4*)(xb + o0 + cb2);
    uint4 r1 = *(const uint4*)(xb + o1 + cb2);
    uint4 r2 = *(const uint4*)(xb + o2 + cb2);
    uint4 r3 = *(const uint4*)(xb + o3 + cb2);
    float v0 = sc0 + sd; v0 = v0 >= 0.f ? v0 : ALPHA * v0;
    float v1 = sc1 + sd; v1 = v1 >= 0.f ? v1 : ALPHA * v1;
    float v2 = sc2 + sd; v2 = v2 >= 0.f ? v2 : ALPHA * v2;
    float v3 = sc3 + sd; v3 = v3 >= 0.f ? v3 : ALPHA * v3;
    float p0 = __expf(v0);
    float p1 = __expf(v1);
    float p2 = __expf(v2);
    float p3 = __expf(v3);
    psum += (p0 + p1) + (p2 + p3);
    fma8(acc, p0, r0);
    fma8(acc, p1, r1);
    fma8(acc, p2, r2);
    fma8(acc, p3, r3);
    j += 8;
  }
  while (j < eEnd) {
    int o0 = ((int)csr16[j]) << 9;
    float sc0 = s_src[(o0 >> 7) + h];
    uint4 r0 = *(const uint4*)(xb + o0 + cb2);
    float v0 = sc0 + sd; v0 = v0 >= 0.f ? v0 : ALPHA * v0;
    float p0 = __expf(v0);
    psum += p0;
    fma8(acc, p0, r0);
    j += 2;
  }

  // combine the two edge-halves
  psum += __shfl_xor(psum, 32);
  #pragma unroll
  for (int k = 0; k < 8; ++k) acc[k] += __shfl_xor(acc[k], 32);

  float inv = 1.f / (psum + 1e-10f);
  float4 o;
  if (half) o = make_float4(acc[4] * inv, acc[5] * inv, acc[6] * inv, acc[7] * inv);
  else      o = make_float4(acc[0] * inv, acc[1] * inv, acc[2] * inv, acc[3] * inv);
  *(float4*)(out + node * COLS + (g << 3) + half * 4) = o;
}

// ---------------------------------------------------------------------------
extern "C" void kernel_launch(void* const* d_in, const int* in_sizes, int n_in,
                              void* d_out, int out_size, void* d_ws, size_t ws_size,
                              hipStream_t stream) {
  const float* x  = (const float*)d_in[0];
  const int*   ei = (const int*)d_in[1];
  const float* W  = (const float*)d_in[2];
  const float* a  = (const float*)d_in[3];
  float* out = (float*)d_out;

  const int n = in_sizes[0] / IN_F;   // 50000
  const int E = in_sizes[1] / 2;      // 800000
  const int nparts = (n + 255) / 256; // 196 scan chunks
  const int GB = (n + 63) / 64;       // 782 gemm blocks

  char* ws = (char*)d_ws;
  size_t off = 0;
  unsigned short* xtb = (unsigned short*)(ws + off); off += (size_t)n * COLS * 2;  // 25.6 MB
  unsigned short* Wb  = (unsigned short*)(ws + off); off += (size_t)HEADS * IN_F * OUT_F * 2;
  float* s_src = (float*)(ws + off);   off += (size_t)n * 4 * 4;
  float* s_dst = (float*)(ws + off);   off += (size_t)n * 4 * 4;
  int* deg = (int*)(ws + off);         off += (size_t)n * 4;
  int* done = (int*)(ws + off);        off += 256;               // scan done-counter
  int* start = (int*)(ws + off);       off += (size_t)n * 4;
  int* part = (int*)(ws + off);        off += (size_t)nparts * 4;
  unsigned short* rank16 = (unsigned short*)(ws + off); off += (size_t)E * 2;
  unsigned short* csr16  = (unsigned short*)(ws + off); off += (size_t)E * 2;

  k_prep<<<nparts, 256, 0, stream>>>(W, Wb, deg, done, n);

  k_big<<<GB + HIST_BLOCKS, 256, 0, stream>>>(x, Wb, a, ei, xtb, s_src, s_dst,
                                              deg, rank16, n, E, GB);

  k_scanA<<<nparts, 256, 0, stream>>>(deg, part, done, n, nparts);
  k_scanB<<<nparts, 256, 0, stream>>>(deg, part, start, n);

  k_scatter<<<(E + 255) / 256, 256, 0, stream>>>(ei, start, rank16, csr16, E);

  k_aggr<<<(n + 1) / 2, 128, 0, stream>>>(csr16, start, deg, s_src, s_dst, xtb, out, n);
}